// Round 5
// baseline (180.672 us; speedup 1.0000x reference)
//
#include <hip/hip_runtime.h>
#include <hip/hip_cooperative_groups.h>
#include <cstdint>

namespace cg = cooperative_groups;

// ---------------------------------------------------------------------------
// JAX PRNG replication (verified bit-exact rounds 1-4, absmax 0.0).
// key(42) -> threefry2x32 key (0,42), jax_threefry_partitionable semantics.
// ---------------------------------------------------------------------------
__host__ __device__ inline void threefry2x32(uint32_t k0, uint32_t k1,
                                             uint32_t x0, uint32_t x1,
                                             uint32_t& o0, uint32_t& o1) {
  const uint32_t ks2 = k0 ^ k1 ^ 0x1BD11BDAu;
  uint32_t v0 = x0 + k0, v1 = x1 + k1;
#define RL(v, r) (((v) << (r)) | ((v) >> (32 - (r))))
#define RND4(a, b, c, d)                                                       \
  v0 += v1; v1 = RL(v1, a); v1 ^= v0;                                          \
  v0 += v1; v1 = RL(v1, b); v1 ^= v0;                                          \
  v0 += v1; v1 = RL(v1, c); v1 ^= v0;                                          \
  v0 += v1; v1 = RL(v1, d); v1 ^= v0;
  RND4(13, 15, 26, 6)  v0 += k1;  v1 += ks2 + 1u;
  RND4(17, 29, 16, 24) v0 += ks2; v1 += k0 + 2u;
  RND4(13, 15, 26, 6)  v0 += k0;  v1 += k1 + 3u;
  RND4(17, 29, 16, 24) v0 += k1;  v1 += ks2 + 4u;
  RND4(13, 15, 26, 6)  v0 += ks2; v1 += k0 + 5u;
#undef RND4
#undef RL
  o0 = v0; o1 = v1;
}

#define IN_F 512
#define OUT_F 512
#define BATCH 512

#define BT 64
#define OT 64
#define KT 32
#define NZ 4
#define KZ (IN_F / NZ)  // 128

// ---------------------------------------------------------------------------
// Single cooperative kernel, 3 phases, grid (8,8,4)=256 blocks x 256 thr
// (1 block/CU -> co-residency guaranteed).
//  A: mask gen (each block: 2 o-rows, bit-exact threefry/softmax/ballot/fixup
//     identical to the verified standalone kernel), M[o][i] in ws.
//  B: min-plus, 64b x 64o x KZ=128 tile, 4x4 register micro-tile (R4
//     structure, LDS-bound ~96cyc/k per CU), z-slice partials in ws.
//  C: fold 4 z-slices (L2-resident) into d_out.
// Eliminates 2 dispatch gaps + 2 launch tails vs the 3-kernel version.
// ---------------------------------------------------------------------------
__global__ __launch_bounds__(256) void fused_kernel(
    const float* __restrict__ x, const float* __restrict__ pw,
    float* __restrict__ M, float* __restrict__ part, float* __restrict__ out,
    uint32_t kb0, uint32_t kb1, uint32_t kl0, uint32_t kl1) {
  const int tid = threadIdx.x;
  const int bid = (blockIdx.z * 8 + blockIdx.y) * 8 + blockIdx.x;  // 0..255

  // ------------------------- Phase A: mask generation -------------------------
  __shared__ unsigned long long words[8];
  __shared__ int cnt;
#pragma unroll 1
  for (int r = 0; r < 2; ++r) {
    const int o = bid * 2 + r;
    if (tid == 0) cnt = 0;
    __syncthreads();
    bool cj[2];
#pragma unroll
    for (int j = 0; j < 2; ++j) {
      const int i = tid + 256 * j;
      const float2 w = ((const float2*)pw)[o * IN_F + i];
      const float mx = fmaxf(w.x, w.y);
      const float e0 = expf(w.x - mx);
      const float e1 = expf(w.y - mx);
      const float p = e1 / (e0 + e1);
      const uint32_t n = (uint32_t)(o * IN_F + i);
      uint32_t h0, h1;
      threefry2x32(kb0, kb1, 0u, n, h0, h1);
      const uint32_t bits = h0 ^ h1;
      const float u = __uint_as_float((bits >> 9) | 0x3F800000u) - 1.0f;
      cj[j] = u < p;
    }
#pragma unroll
    for (int j = 0; j < 2; ++j) {
      const unsigned long long bal = __ballot(cj[j]);
      if ((tid & 63) == 0) {
        words[(tid >> 6) + 4 * j] = bal;
        atomicAdd(&cnt, __popcll(bal));
      }
    }
    __syncthreads();
    if (cnt == 0 && tid == 0) {
      uint32_t c0, c1;
      threefry2x32(kl0, kl1, 0u, (uint32_t)o, c0, c1);
      const uint32_t col = (c0 ^ c1) & (IN_F - 1);
      words[col >> 6] |= (1ull << (col & 63u));
    }
    __syncthreads();
#pragma unroll
    for (int j = 0; j < 2; ++j) {
      const int i = tid + 256 * j;
      const bool sel = (words[i >> 6] >> (i & 63)) & 1ull;
      M[o * IN_F + i] = sel ? 0.0f : 1e9f;
    }
    __syncthreads();
  }

  __threadfence();
  cg::this_grid().sync();

  // ------------------------- Phase B: tiled min-plus --------------------------
  __shared__ float xs[KT][BT + 4];  // [k][b], stride 68 (16B-aligned rows)
  __shared__ float ms[KT][OT + 4];  // [k][o]

  const int tx = tid & 15;   // b quad: b = b0 + 4*tx + i
  const int ty = tid >> 4;   // o quad: o = o0 + 4*ty + j
  const int b0 = blockIdx.x * BT;
  const int o0 = blockIdx.y * OT;
  const int kb = blockIdx.z * KZ;

  const int lr = tid >> 3;       // 0..31: staging row
  const int lc = (tid & 7) * 4;  // 0..28: staging k offset (float4)

  float4 acc[4];
#pragma unroll
  for (int i = 0; i < 4; ++i) acc[i] = make_float4(1e30f, 1e30f, 1e30f, 1e30f);

  for (int kt = 0; kt < KZ; kt += KT) {
#pragma unroll
    for (int j = 0; j < 2; ++j) {
      const int rr = j * 32 + lr;
      const float4 v = *(const float4*)&x[(b0 + rr) * IN_F + kb + kt + lc];
      xs[lc + 0][rr] = v.x; xs[lc + 1][rr] = v.y;
      xs[lc + 2][rr] = v.z; xs[lc + 3][rr] = v.w;
      const float4 w = *(const float4*)&M[(o0 + rr) * IN_F + kb + kt + lc];
      ms[lc + 0][rr] = w.x; ms[lc + 1][rr] = w.y;
      ms[lc + 2][rr] = w.z; ms[lc + 3][rr] = w.w;
    }
    __syncthreads();
#pragma unroll 8
    for (int k = 0; k < KT; ++k) {
      const float4 xv = *(const float4*)&xs[k][tx * 4];  // clean b128
      const float4 mv = *(const float4*)&ms[k][ty * 4];  // broadcast b128
#pragma unroll
      for (int i = 0; i < 4; ++i) {
        const float xi = (i == 0) ? xv.x : (i == 1) ? xv.y : (i == 2) ? xv.z : xv.w;
        acc[i].x = fminf(acc[i].x, xi + mv.x);
        acc[i].y = fminf(acc[i].y, xi + mv.y);
        acc[i].z = fminf(acc[i].z, xi + mv.z);
        acc[i].w = fminf(acc[i].w, xi + mv.w);
      }
    }
    __syncthreads();
  }

  float* pz = part + (size_t)blockIdx.z * (BATCH * OUT_F);
#pragma unroll
  for (int i = 0; i < 4; ++i)
    *(float4*)&pz[(size_t)(b0 + 4 * tx + i) * OUT_F + o0 + 4 * ty] = acc[i];

  __threadfence();
  cg::this_grid().sync();

  // ------------------------- Phase C: z-slice fold ----------------------------
  const int g = bid * 256 + tid;  // float4 index, covers 512*512 floats
  float4 a = ((const float4*)part)[g];
#pragma unroll
  for (int z = 1; z < NZ; ++z) {
    const float4 b = ((const float4*)(part + (size_t)z * BATCH * OUT_F))[g];
    a.x = fminf(a.x, b.x); a.y = fminf(a.y, b.y);
    a.z = fminf(a.z, b.z); a.w = fminf(a.w, b.w);
  }
  ((float4*)out)[g] = a;
}

extern "C" void kernel_launch(void* const* d_in, const int* in_sizes, int n_in,
                              void* d_out, int out_size, void* d_ws, size_t ws_size,
                              hipStream_t stream) {
  (void)in_sizes; (void)n_in; (void)out_size; (void)ws_size;
  const float* x = (const float*)d_in[0];   // [512, 512]
  const float* pw = (const float*)d_in[1];  // [512, 512, 2]
  float* M = (float*)d_ws;                       // 1 MB
  float* part = (float*)d_ws + BATCH * OUT_F;    // 4 MB (NZ=4 slices)
  float* out = (float*)d_out;

  uint32_t kb0, kb1, kf0, kf1, kl0, kl1;
  threefry2x32(0u, 42u, 0u, 0u, kb0, kb1);   // k_bern = hash(key; 0,0)
  threefry2x32(0u, 42u, 0u, 1u, kf0, kf1);   // k_fix  = hash(key; 0,1)
  threefry2x32(kf0, kf1, 0u, 1u, kl0, kl1);  // randint lower-bits key

  void* args[] = {(void*)&x, (void*)&pw, (void*)&M, (void*)&part, (void*)&out,
                  (void*)&kb0, (void*)&kb1, (void*)&kl0, (void*)&kl1};
  hipLaunchCooperativeKernel((const void*)fused_kernel,
                             dim3(BATCH / BT, OUT_F / OT, NZ), dim3(256),
                             args, 0, stream);
}

// Round 6
// 98.169 us; speedup vs baseline: 1.8404x; 1.8404x over previous
//
#include <hip/hip_runtime.h>
#include <cstdint>

// ---------------------------------------------------------------------------
// JAX PRNG replication (verified bit-exact rounds 1-5, absmax 0.0).
// key(42) -> threefry2x32 key (0,42), jax_threefry_partitionable semantics.
// ---------------------------------------------------------------------------
__host__ __device__ inline void threefry2x32(uint32_t k0, uint32_t k1,
                                             uint32_t x0, uint32_t x1,
                                             uint32_t& o0, uint32_t& o1) {
  const uint32_t ks2 = k0 ^ k1 ^ 0x1BD11BDAu;
  uint32_t v0 = x0 + k0, v1 = x1 + k1;
#define RL(v, r) (((v) << (r)) | ((v) >> (32 - (r))))
#define RND4(a, b, c, d)                                                       \
  v0 += v1; v1 = RL(v1, a); v1 ^= v0;                                          \
  v0 += v1; v1 = RL(v1, b); v1 ^= v0;                                          \
  v0 += v1; v1 = RL(v1, c); v1 ^= v0;                                          \
  v0 += v1; v1 = RL(v1, d); v1 ^= v0;
  RND4(13, 15, 26, 6)  v0 += k1;  v1 += ks2 + 1u;
  RND4(17, 29, 16, 24) v0 += ks2; v1 += k0 + 2u;
  RND4(13, 15, 26, 6)  v0 += k0;  v1 += k1 + 3u;
  RND4(17, 29, 16, 24) v0 += k1;  v1 += ks2 + 4u;
  RND4(13, 15, 26, 6)  v0 += ks2; v1 += k0 + 5u;
#undef RND4
#undef RL
  o0 = v0; o1 = v1;
}

#define IN_F 512
#define OUT_F 512
#define BATCH 512

// ---------------------------------------------------------------------------
// Prep kernel, grid 576 x 256 thr.
//  Blocks 0..511: mask gen for row o=bid (verified bit-exact logic from R5's
//    256-thread phase A), written o-quad-packed: Mp[og][k] = f4 of
//    M[4og..4og+3][k] (so the min-plus kernel reads one wave-uniform f4/k).
//  Blocks 512..575: transpose x -> xT[k][b] via 64x64 LDS tile (stride 65:
//    2-way bank aliasing only = free), both global sides coalesced f4.
// ---------------------------------------------------------------------------
__global__ __launch_bounds__(256) void prep_kernel(
    const float* __restrict__ x, const float* __restrict__ pw,
    float* __restrict__ Mp, float* __restrict__ xT,
    uint32_t kb0, uint32_t kb1, uint32_t kl0, uint32_t kl1) {
  const int tid = threadIdx.x;
  if (blockIdx.x < 512) {
    const int o = blockIdx.x;
    __shared__ unsigned long long words[8];
    __shared__ int cnt;
    if (tid == 0) cnt = 0;
    __syncthreads();
    bool cj[2];
#pragma unroll
    for (int j = 0; j < 2; ++j) {
      const int i = tid + 256 * j;
      const float2 w = ((const float2*)pw)[o * IN_F + i];
      const float mx = fmaxf(w.x, w.y);
      const float e0 = expf(w.x - mx);
      const float e1 = expf(w.y - mx);
      const float p = e1 / (e0 + e1);
      uint32_t h0, h1;
      threefry2x32(kb0, kb1, 0u, (uint32_t)(o * IN_F + i), h0, h1);
      const uint32_t bits = h0 ^ h1;
      const float u = __uint_as_float((bits >> 9) | 0x3F800000u) - 1.0f;
      cj[j] = u < p;
    }
#pragma unroll
    for (int j = 0; j < 2; ++j) {
      const unsigned long long bal = __ballot(cj[j]);
      if ((tid & 63) == 0) {
        words[(tid >> 6) + 4 * j] = bal;
        atomicAdd(&cnt, __popcll(bal));
      }
    }
    __syncthreads();
    if (cnt == 0 && tid == 0) {
      uint32_t c0, c1;
      threefry2x32(kl0, kl1, 0u, (uint32_t)o, c0, c1);
      const uint32_t col = (c0 ^ c1) & (IN_F - 1);
      words[col >> 6] |= (1ull << (col & 63u));
    }
    __syncthreads();
#pragma unroll
    for (int j = 0; j < 2; ++j) {
      const int i = tid + 256 * j;
      const bool sel = (words[i >> 6] >> (i & 63)) & 1ull;
      Mp[((size_t)(o >> 2) * IN_F + i) * 4 + (o & 3)] = sel ? 0.0f : 1e9f;
    }
  } else {
    const int t = blockIdx.x - 512;
    const int ti = t >> 3, tj = t & 7;  // ti: b-tile, tj: k-tile
    __shared__ float tile[64][65];
    const int r0 = tid >> 4;            // 0..15
    const int c4 = (tid & 15) * 4;      // 0..60
#pragma unroll
    for (int rr = 0; rr < 4; ++rr) {
      const int r = r0 + 16 * rr;  // b within tile
      const float4 v = *(const float4*)&x[(size_t)(64 * ti + r) * IN_F + 64 * tj + c4];
      tile[r][c4 + 0] = v.x; tile[r][c4 + 1] = v.y;
      tile[r][c4 + 2] = v.z; tile[r][c4 + 3] = v.w;
    }
    __syncthreads();
#pragma unroll
    for (int it = 0; it < 4; ++it) {
      const int kr = r0 + 16 * it;  // k within tile
      const int b4 = c4;            // b quad within tile
      float4 v;
      v.x = tile[b4 + 0][kr]; v.y = tile[b4 + 1][kr];
      v.z = tile[b4 + 2][kr]; v.w = tile[b4 + 3][kr];
      *(float4*)&xT[(size_t)(64 * tj + kr) * BATCH + 64 * ti + b4] = v;
    }
  }
}

// ---------------------------------------------------------------------------
// Min-plus, LDS-free hot loop. Grid 256 blocks x 256 thr; block = (b-half bg,
// o-quad og); wave = k-quarter (128 k). Lane owns a b-quad (coalesced f4 xT
// load, 1 KB/wave-inst); mask f4 is wave-uniform (scalarizes / broadcasts).
// Per k per lane: 16 add + 16 min = 32 VALU -> 4096 VALU insts/thread = the
// 3.4 us VALU floor at 1 wave/SIMD. Tiny LDS fold of 4 k-quarters at the end.
// ---------------------------------------------------------------------------
__global__ __launch_bounds__(256) void minplus_kernel(
    const float* __restrict__ xT, const float* __restrict__ Mp,
    float* __restrict__ out) {
  const int tid = threadIdx.x;
  const int lane = tid & 63;
  const int w = tid >> 6;      // k-quarter 0..3
  const int bg = blockIdx.x & 1;
  const int og = blockIdx.x >> 1;  // 0..127
  const int bbase = 256 * bg + 4 * lane;
  const int kbase = 128 * w;

  const float4* xp = (const float4*)(xT + (size_t)kbase * BATCH + bbase);
  const float4* mp = (const float4*)Mp + (size_t)og * IN_F + kbase;

  float4 acc[4];
#pragma unroll
  for (int q = 0; q < 4; ++q) acc[q] = make_float4(1e30f, 1e30f, 1e30f, 1e30f);

#pragma unroll 8
  for (int k = 0; k < 128; ++k) {
    const float4 xv = xp[(size_t)k * (BATCH / 4)];  // coalesced: 4 b's/lane
    const float4 mv = mp[k];                        // wave-uniform o-quad
#pragma unroll
    for (int q = 0; q < 4; ++q) {
      const float xb = (q == 0) ? xv.x : (q == 1) ? xv.y : (q == 2) ? xv.z : xv.w;
      acc[q].x = fminf(acc[q].x, xb + mv.x);
      acc[q].y = fminf(acc[q].y, xb + mv.y);
      acc[q].z = fminf(acc[q].z, xb + mv.z);
      acc[q].w = fminf(acc[q].w, xb + mv.w);
    }
  }

  // fold 4 k-quarter partials: part[w][q][lane], all accesses lane-contiguous
  __shared__ float4 part[4][4][64];  // 16 KB
#pragma unroll
  for (int q = 0; q < 4; ++q) part[w][q][lane] = acc[q];
  __syncthreads();

  // thread (w, lane) -> output row b = bbase + w (q == w), o-quad og
  float4 r = part[0][w][lane];
#pragma unroll
  for (int w2 = 1; w2 < 4; ++w2) {
    const float4 p = part[w2][w][lane];
    r.x = fminf(r.x, p.x); r.y = fminf(r.y, p.y);
    r.z = fminf(r.z, p.z); r.w = fminf(r.w, p.w);
  }
  *(float4*)&out[(size_t)(256 * bg + 4 * lane + w) * OUT_F + 4 * og] = r;
}

extern "C" void kernel_launch(void* const* d_in, const int* in_sizes, int n_in,
                              void* d_out, int out_size, void* d_ws, size_t ws_size,
                              hipStream_t stream) {
  (void)in_sizes; (void)n_in; (void)out_size; (void)ws_size;
  const float* x = (const float*)d_in[0];   // [512, 512]
  const float* pw = (const float*)d_in[1];  // [512, 512, 2]
  float* Mp = (float*)d_ws;                     // 1 MB: [128 og][512 k] f4
  float* xT = (float*)d_ws + BATCH * IN_F;      // 1 MB: [512 k][512 b]
  float* out = (float*)d_out;

  uint32_t kb0, kb1, kf0, kf1, kl0, kl1;
  threefry2x32(0u, 42u, 0u, 0u, kb0, kb1);   // k_bern = hash(key; 0,0)
  threefry2x32(0u, 42u, 0u, 1u, kf0, kf1);   // k_fix  = hash(key; 0,1)
  threefry2x32(kf0, kf1, 0u, 1u, kl0, kl1);  // randint lower-bits key

  prep_kernel<<<dim3(576), dim3(256), 0, stream>>>(x, pw, Mp, xT,
                                                   kb0, kb1, kl0, kl1);
  minplus_kernel<<<dim3(256), dim3(256), 0, stream>>>(xT, Mp, out);
}